// Round 3
// baseline (9119.678 us; speedup 1.0000x reference)
//
#include <hip/hip_runtime.h>
#include <hip/hip_cooperative_groups.h>
#include <math.h>

namespace cg = cooperative_groups;

// Paraphraser seq2seq: bi-LSTM encoder + attention decoder + fused vocab log-softmax.
// Shapes: S=40, B=32, T=40, E=256, H=512, V=50000. All fp32.
// Round 3 == Round 2 resubmit (broker timeout, kernel never measured):
// persistent cooperative kernels for enc/dec recurrence (was 118 launches).

#define S_LEN 40
#define BATCH 32
#define EMB   256
#define HID   512
#define G4H   2048          // 4*H
#define NVOC  50000
#define NDEC  39            // T-1 decoder steps
#define NCHUNK 196          // ceil(50000/256)
#define MROWS 1248          // NDEC*BATCH real rows into vocab GEMM
#define MPAD  1280          // padded to 20*64 row tiles

__device__ __forceinline__ float sigf(float x) { return 1.f / (1.f + expf(-x)); }

// ---------------- embedding gather ----------------
__global__ __launch_bounds__(256) void k_embed(
    const int* __restrict__ src_ids, const int* __restrict__ tgt_ids,
    const float* __restrict__ src_emb, const float* __restrict__ tgt_emb,
    float* __restrict__ src_e, float* __restrict__ tgt_e)
{
  int row = blockIdx.x, tid = threadIdx.x;
  if (row < S_LEN*BATCH) {
    int id = src_ids[row];
    src_e[(size_t)row*EMB + tid] = src_emb[(size_t)id*EMB + tid];
  } else {
    int r = row - S_LEN*BATCH;
    int id = tgt_ids[r];
    tgt_e[(size_t)r*EMB + tid] = tgt_emb[(size_t)id*EMB + tid];
  }
}

// ---------------- generic GEMM: C = A @ W^T (+bias) ----------------
// BM=32, BN=256, BK=16, 256 threads, micro-tile 4x8.
// rev!=0: A-row remap (reversed-sequence enc projection), needs gridDim.y==40.
__global__ __launch_bounds__(256) void k_gemm(
    const float* __restrict__ A, const float* __restrict__ W,
    const float* __restrict__ bias, float* __restrict__ C,
    int N, int K, int ldw, int rev)
{
  __shared__ float As[16][36];
  __shared__ float Ws[16][256];
  const int tid = threadIdx.x;
  const int tx = tid & 31, ty = tid >> 5;
  const int bn = (int)blockIdx.x << 8;
  const int bmi = (int)blockIdx.y;
  const int bm = bmi << 5;
  const int arow0 = rev ? ((S_LEN - 1 - bmi) << 5) : bm;

  float acc[4][8];
#pragma unroll
  for (int i = 0; i < 4; i++)
#pragma unroll
    for (int j = 0; j < 8; j++) acc[i][j] = 0.f;

  const int ml = tid >> 3, kl = (tid & 7) << 1;
  const float* aptr = A + (size_t)(arow0 + ml)*K + kl;
  const float* wptr = W + (size_t)(bn + tid)*ldw;

  for (int k0 = 0; k0 < K; k0 += 16) {
    const float2 av  = *(const float2*)(aptr + k0);
    const float4 w0v = *(const float4*)(wptr + k0);
    const float4 w1v = *(const float4*)(wptr + k0 + 4);
    const float4 w2v = *(const float4*)(wptr + k0 + 8);
    const float4 w3v = *(const float4*)(wptr + k0 + 12);
    __syncthreads();
    As[kl][ml]   = av.x;
    As[kl+1][ml] = av.y;
    const float wt[16] = {w0v.x,w0v.y,w0v.z,w0v.w, w1v.x,w1v.y,w1v.z,w1v.w,
                          w2v.x,w2v.y,w2v.z,w2v.w, w3v.x,w3v.y,w3v.z,w3v.w};
#pragma unroll
    for (int kk = 0; kk < 16; kk++) Ws[kk][tid] = wt[kk];
    __syncthreads();
#pragma unroll
    for (int kk = 0; kk < 16; kk++) {
      const float4 a4 = *(const float4*)&As[kk][ty << 2];
      const float4 b0 = *(const float4*)&Ws[kk][tx << 2];
      const float4 b1 = *(const float4*)&Ws[kk][128 + (tx << 2)];
      const float ar[4] = {a4.x, a4.y, a4.z, a4.w};
      const float br[8] = {b0.x, b0.y, b0.z, b0.w, b1.x, b1.y, b1.z, b1.w};
#pragma unroll
      for (int i = 0; i < 4; i++)
#pragma unroll
        for (int j = 0; j < 8; j++) acc[i][j] += ar[i]*br[j];
    }
  }
  float4 bb0 = {0,0,0,0}, bb1 = {0,0,0,0};
  if (bias) {
    bb0 = *(const float4*)&bias[bn + (tx << 2)];
    bb1 = *(const float4*)&bias[bn + 128 + (tx << 2)];
  }
#pragma unroll
  for (int i = 0; i < 4; i++) {
    const int row = bm + (ty << 2) + i;
    float4 o0 = {acc[i][0]+bb0.x, acc[i][1]+bb0.y, acc[i][2]+bb0.z, acc[i][3]+bb0.w};
    float4 o1 = {acc[i][4]+bb1.x, acc[i][5]+bb1.y, acc[i][6]+bb1.z, acc[i][7]+bb1.w};
    *(float4*)&C[(size_t)row*N + bn + (tx << 2)] = o0;
    *(float4*)&C[(size_t)row*N + bn + 128 + (tx << 2)] = o1;
  }
}

// ---------------- persistent encoder (cooperative, grid 256 x 256) ----------------
// blocks [0,128)=fwd, [128,256)=bwd. wave = one hidden unit j (4 per block).
// lane = r(batch, 0..31) x khalf(0/1); c-state in registers of khalf==0 lanes.
// h history in packed layout hp[t][k/4][r][4] (lane-dense float4 reads, no LDS).
__global__ __launch_bounds__(256) void k_enc(
    const float* __restrict__ xpf, const float* __restrict__ xpb,
    const float* __restrict__ Whf, const float* __restrict__ Whb,
    float* __restrict__ hpf, float* __restrict__ hpb,
    float* __restrict__ hcat, float* __restrict__ ccat)
{
  cg::grid_group grid = cg::this_grid();
  const int blk = blockIdx.x;
  const int dir = blk >> 7;
  const int ub  = blk & 127;
  const int tid = threadIdx.x;
  const int w = tid >> 6, lane = tid & 63;
  const int r = lane & 31, half = lane >> 5;
  const int j = ub*4 + w;              // hidden unit in [0,512)
  const int kbase = half << 8;         // 0 or 256

  const float* xp  = dir ? xpb : xpf;
  const float* Whh = dir ? Whb : Whf;
  float* hp = dir ? hpb : hpf;

  const float* w0 = Whh + (size_t)(0*HID + j)*HID + kbase;
  const float* w1 = Whh + (size_t)(1*HID + j)*HID + kbase;
  const float* w2 = Whh + (size_t)(2*HID + j)*HID + kbase;
  const float* w3 = Whh + (size_t)(3*HID + j)*HID + kbase;

  float creg = 0.f;
  for (int t = 0; t < S_LEN; t++) {
    float a0 = 0.f, a1 = 0.f, a2 = 0.f, a3 = 0.f;
    if (t > 0) {
      const float* hb = hp + (size_t)(t-1)*16384 + (kbase << 5) + (r << 2);
#pragma unroll 4
      for (int kk = 0; kk < 256; kk += 4) {
        const float4 hv = *(const float4*)(hb + (kk << 5));
        const float4 v0 = *(const float4*)(w0 + kk);
        const float4 v1 = *(const float4*)(w1 + kk);
        const float4 v2 = *(const float4*)(w2 + kk);
        const float4 v3 = *(const float4*)(w3 + kk);
        a0 += v0.x*hv.x + v0.y*hv.y + v0.z*hv.z + v0.w*hv.w;
        a1 += v1.x*hv.x + v1.y*hv.y + v1.z*hv.z + v1.w*hv.w;
        a2 += v2.x*hv.x + v2.y*hv.y + v2.z*hv.z + v2.w*hv.w;
        a3 += v3.x*hv.x + v3.y*hv.y + v3.z*hv.z + v3.w*hv.w;
      }
    }
    // merge the two K-halves
    a0 += __shfl_down(a0, 32);
    a1 += __shfl_down(a1, 32);
    a2 += __shfl_down(a2, 32);
    a3 += __shfl_down(a3, 32);
    if (half == 0) {
      const float* xrow = xp + (size_t)(t*BATCH + r)*G4H;
      const float gi = a0 + xrow[j];
      const float gf = a1 + xrow[HID + j];
      const float gg = a2 + xrow[2*HID + j];
      const float go = a3 + xrow[3*HID + j];
      const float cn = sigf(gf)*creg + sigf(gi)*tanhf(gg);
      const float hn = sigf(go)*tanhf(cn);
      creg = cn;
      hp[(size_t)t*16384 + (j >> 2)*128 + (r << 2) + (j & 3)] = hn;
      if (t == S_LEN-1) {
        hcat[r*1024 + dir*HID + j] = hn;
        ccat[r*1024 + dir*HID + j] = cn;
      }
    }
    grid.sync();
  }
}

// ---------------- build enc_hidden (B,S,2H) from packed h histories ----------------
__global__ __launch_bounds__(256) void k_concat(
    const float* __restrict__ hpf, const float* __restrict__ hpb,
    float* __restrict__ ench)
{
  const int blk = blockIdx.x, tid = threadIdx.x;   // blk = b*40+s
  const int b = blk / S_LEN, s = blk - b*S_LEN;
#pragma unroll
  for (int q = 0; q < 4; q++) {
    const int d = tid + (q << 8);
    float v;
    if (d < HID) v = hpf[(size_t)s*16384 + (d >> 2)*128 + (b << 2) + (d & 3)];
    else {
      const int d2 = d - HID;
      v = hpb[(size_t)(S_LEN-1-s)*16384 + (d2 >> 2)*128 + (b << 2) + (d2 & 3)];
    }
    ench[(size_t)blk*1024 + d] = v;
  }
}

// ---------------- persistent decoder (cooperative, grid 256 x 256) ----------------
// Per step: phase A (LSTM, block = 2 hidden units, 8-way K-split across waves/halves,
// LDS reduce, c in registers of tid<64) -> sync -> phase B (attention, blocks 0..31,
// one per batch elem) -> sync -> phase C (combine, block = 2 output cols, 8-way
// K-split) -> sync. Operands in packed transposed buffers:
//   aop  [1024/4][r][4]: k<512 = o_prev, k>=512 = h_prev  (LSTM input)
//   xcomb[1536/4][r][4]: k<512 = h_t,   k>=512 = ctx_t    (combine input)
__global__ __launch_bounds__(256) void k_dec(
    const float* __restrict__ xproj, const float* __restrict__ Wih, const float* __restrict__ Whh,
    const float* __restrict__ Wcomb, const float* __restrict__ encp, const float* __restrict__ ench,
    const float* __restrict__ masks, const float* __restrict__ h0, const float* __restrict__ c0,
    float* __restrict__ aop, float* __restrict__ xcomb, float* __restrict__ outs)
{
  cg::grid_group grid = cg::this_grid();
  __shared__ float redA[4][2][4][32];
  __shared__ float redC[4][2][32];
  __shared__ float hl[HID];
  __shared__ float sc[S_LEN];

  const int blk = blockIdx.x, tid = threadIdx.x;
  const int w = tid >> 6, lane = tid & 63;
  const int r = lane & 31, half = lane >> 5;
  const int j0 = blk*2;

  // ---- phase-A weight pointers (t-invariant). K-slice: 128 wide. ----
  const int kbA = w*256 + half*128;     // in [0,1024)
  const float* wA[8];
#pragma unroll
  for (int u = 0; u < 2; u++)
#pragma unroll
    for (int g = 0; g < 4; g++) {
      const int row = g*HID + j0 + u;
      wA[u*4+g] = (kbA < HID) ? (Wih + (size_t)row*768 + 256 + kbA)
                              : (Whh + (size_t)row*HID + (kbA - HID));
    }
  const float* habase = aop + (kbA << 5) + (r << 2);

  // ---- phase-C pointers. K-slice: 192 wide over K=1536. ----
  const int kbC = w*384 + half*192;
  const float* wC0 = Wcomb + (size_t)(j0  )*1536 + kbC;
  const float* wC1 = Wcomb + (size_t)(j0+1)*1536 + kbC;
  const float* hcbase = xcomb + (kbC << 5) + (r << 2);

  // ---- prologue: c-state + initial aop (o_{-1}=0, h_0) ----
  float creg = 0.f;
  if (tid < 64) {
    const int uh = tid >> 5, rr = tid & 31;
    const int j = j0 + uh;
    creg = c0[rr*HID + j];
    aop[(128 + (j >> 2))*128 + (rr << 2) + (j & 3)] = h0[rr*HID + j];
    aop[((j >> 2))*128 + (rr << 2) + (j & 3)] = 0.f;
  }
  grid.sync();

  for (int t = 0; t < NDEC; t++) {
    // ================= A: LSTM gates =================
    {
      float acc8[8];
#pragma unroll
      for (int p = 0; p < 8; p++) acc8[p] = 0.f;
#pragma unroll 2
      for (int kk = 0; kk < 128; kk += 4) {
        const float4 hv = *(const float4*)(habase + (kk << 5));
#pragma unroll
        for (int p = 0; p < 8; p++) {
          const float4 wv = *(const float4*)(wA[p] + kk);
          acc8[p] += wv.x*hv.x + wv.y*hv.y + wv.z*hv.z + wv.w*hv.w;
        }
      }
#pragma unroll
      for (int p = 0; p < 8; p++) acc8[p] += __shfl_down(acc8[p], 32);
      if (half == 0) {
#pragma unroll
        for (int p = 0; p < 8; p++) redA[w][p >> 2][p & 3][r] = acc8[p];
      }
    }
    __syncthreads();
    if (tid < 64) {
      const int uh = tid >> 5, rr = tid & 31, j = j0 + uh;
      const float* xrow = xproj + (size_t)(t*BATCH + rr)*G4H;
      float g4[4];
#pragma unroll
      for (int g = 0; g < 4; g++)
        g4[g] = xrow[g*HID + j] + redA[0][uh][g][rr] + redA[1][uh][g][rr]
                                + redA[2][uh][g][rr] + redA[3][uh][g][rr];
      const float cn = sigf(g4[1])*creg + sigf(g4[0])*tanhf(g4[2]);
      const float hn = sigf(g4[3])*tanhf(cn);
      creg = cn;
      xcomb[(j >> 2)*128 + (rr << 2) + (j & 3)] = hn;            // combine operand (h part)
      aop[(128 + (j >> 2))*128 + (rr << 2) + (j & 3)] = hn;      // next LSTM operand (h part)
    }
    grid.sync();

    // ================= B: attention (blocks 0..31, one per batch elem) =================
    if (blk < BATCH) {
      const int b = blk;
      if (tid < 128) ((float4*)hl)[tid] = *(const float4*)&xcomb[tid*128 + (b << 2)];
      __syncthreads();
      for (int s = w; s < S_LEN; s += 4) {
        const float* ep = encp + ((size_t)b*S_LEN + s)*HID;
        float part = 0.f;
#pragma unroll
        for (int k = 0; k < 8; k++) part += ep[lane + (k << 6)]*hl[lane + (k << 6)];
#pragma unroll
        for (int m = 32; m >= 1; m >>= 1) part += __shfl_xor(part, m, 64);
        if (lane == 0) sc[s] = (masks[b*S_LEN + s] > 0.f) ? -INFINITY : part;
      }
      __syncthreads();
      float mx = -INFINITY;
      for (int s2 = 0; s2 < S_LEN; s2++) mx = fmaxf(mx, sc[s2]);
      float sm = 0.f;
      for (int s2 = 0; s2 < S_LEN; s2++) sm += expf(sc[s2] - mx);
      const float inv = 1.f/sm;
      const float myatt = (tid < S_LEN) ? expf(sc[tid] - mx)*inv : 0.f;
      __syncthreads();
      if (tid < S_LEN) sc[tid] = myatt;
      __syncthreads();
#pragma unroll
      for (int q = 0; q < 4; q++) {
        const int d = tid + (q << 8);
        float cd = 0.f;
        for (int s = 0; s < S_LEN; s++) cd += sc[s]*ench[((size_t)b*S_LEN + s)*1024 + d];
        const int k = HID + d;
        xcomb[(k >> 2)*128 + (b << 2) + (k & 3)] = cd;           // combine operand (ctx part)
      }
    }
    grid.sync();

    // ================= C: combine o_t = tanh([h|ctx] @ Wcomb^T) =================
    {
      float ca = 0.f, cb = 0.f;
#pragma unroll 2
      for (int kk = 0; kk < 192; kk += 4) {
        const float4 hv = *(const float4*)(hcbase + (kk << 5));
        const float4 v0 = *(const float4*)(wC0 + kk);
        const float4 v1 = *(const float4*)(wC1 + kk);
        ca += v0.x*hv.x + v0.y*hv.y + v0.z*hv.z + v0.w*hv.w;
        cb += v1.x*hv.x + v1.y*hv.y + v1.z*hv.z + v1.w*hv.w;
      }
      ca += __shfl_down(ca, 32);
      cb += __shfl_down(cb, 32);
      if (half == 0) { redC[w][0][r] = ca; redC[w][1][r] = cb; }
    }
    __syncthreads();
    if (tid < 64) {
      const int uh = tid >> 5, rr = tid & 31, j = j0 + uh;
      const float o = tanhf(redC[0][uh][rr] + redC[1][uh][rr] + redC[2][uh][rr] + redC[3][uh][rr]);
      aop[(j >> 2)*128 + (rr << 2) + (j & 3)] = o;               // next LSTM operand (o part)
      outs[(size_t)(t*BATCH + rr)*HID + j] = o;                  // vocab GEMM input (row-major)
    }
    grid.sync();
  }
}

// ---------------- vocab GEMM with fused online log-softmax partials ----------------
__global__ __launch_bounds__(256) void k_vocab(
    const float* __restrict__ A, const float* __restrict__ W,
    const int* __restrict__ ptgt,
    float* __restrict__ pmax, float* __restrict__ psum, float* __restrict__ picked)
{
  __shared__ float As[16][68];
  __shared__ float Ws[16][256];
  const int tid = threadIdx.x;
  const int tx = tid & 31, ty = tid >> 5;
  const int bn = (int)blockIdx.x << 8;
  const int bm = (int)blockIdx.y << 6;

  float acc[8][8];
#pragma unroll
  for (int i = 0; i < 8; i++)
#pragma unroll
    for (int j = 0; j < 8; j++) acc[i][j] = 0.f;

  const int ml = tid >> 2, kl = (tid & 3) << 2;
  const float* aptr = A + (size_t)(bm + ml)*HID + kl;
  int wrow = bn + tid; if (wrow >= NVOC) wrow = NVOC - 1;
  const float* wptr = W + (size_t)wrow*HID;

  for (int k0 = 0; k0 < HID; k0 += 16) {
    const float4 av  = *(const float4*)(aptr + k0);
    const float4 w0v = *(const float4*)(wptr + k0);
    const float4 w1v = *(const float4*)(wptr + k0 + 4);
    const float4 w2v = *(const float4*)(wptr + k0 + 8);
    const float4 w3v = *(const float4*)(wptr + k0 + 12);
    __syncthreads();
    As[kl][ml] = av.x; As[kl+1][ml] = av.y; As[kl+2][ml] = av.z; As[kl+3][ml] = av.w;
    const float wt[16] = {w0v.x,w0v.y,w0v.z,w0v.w, w1v.x,w1v.y,w1v.z,w1v.w,
                          w2v.x,w2v.y,w2v.z,w2v.w, w3v.x,w3v.y,w3v.z,w3v.w};
#pragma unroll
    for (int kk = 0; kk < 16; kk++) Ws[kk][tid] = wt[kk];
    __syncthreads();
#pragma unroll
    for (int kk = 0; kk < 16; kk++) {
      const float4 a0 = *(const float4*)&As[kk][ty << 3];
      const float4 a1 = *(const float4*)&As[kk][(ty << 3) + 4];
      const float4 b0 = *(const float4*)&Ws[kk][tx << 2];
      const float4 b1 = *(const float4*)&Ws[kk][128 + (tx << 2)];
      const float ar[8] = {a0.x,a0.y,a0.z,a0.w, a1.x,a1.y,a1.z,a1.w};
      const float br[8] = {b0.x,b0.y,b0.z,b0.w, b1.x,b1.y,b1.z,b1.w};
#pragma unroll
      for (int i = 0; i < 8; i++)
#pragma unroll
        for (int j = 0; j < 8; j++) acc[i][j] += ar[i]*br[j];
    }
  }
#pragma unroll
  for (int i = 0; i < 8; i++) {
    const int row = bm + (ty << 3) + i;
    float mx = -INFINITY;
#pragma unroll
    for (int j = 0; j < 8; j++) {
      const int col = bn + ((j < 4) ? (tx << 2) + j : 128 + (tx << 2) + j - 4);
      if (col < NVOC) mx = fmaxf(mx, acc[i][j]);
    }
#pragma unroll
    for (int m = 16; m >= 1; m >>= 1) mx = fmaxf(mx, __shfl_xor(mx, m, 32));
    float sm = 0.f;
#pragma unroll
    for (int j = 0; j < 8; j++) {
      const int col = bn + ((j < 4) ? (tx << 2) + j : 128 + (tx << 2) + j - 4);
      if (col < NVOC) sm += expf(acc[i][j] - mx);
    }
#pragma unroll
    for (int m = 16; m >= 1; m >>= 1) sm += __shfl_xor(sm, m, 32);
    if (tx == 0) {
      pmax[(size_t)row*NCHUNK + blockIdx.x] = mx;
      psum[(size_t)row*NCHUNK + blockIdx.x] = sm;
    }
    if (row < MROWS) {
      const int tt = row >> 5, bb = row & 31;
      const int tv = ptgt[(tt + 1)*BATCH + bb];
      const int rel = tv - bn;
      if (rel >= 0 && rel < 256) {
#pragma unroll
        for (int j = 0; j < 8; j++) {
          const int cl = (j < 4) ? (tx << 2) + j : 128 + (tx << 2) + j - 4;
          if (cl == rel) picked[row] = acc[i][j];
        }
      }
    }
  }
}

// ---------------- final reduce ----------------
__global__ __launch_bounds__(256) void k_final(
    const float* __restrict__ pmax, const float* __restrict__ psum,
    const float* __restrict__ picked, const int* __restrict__ ptgt,
    float* __restrict__ out)
{
  __shared__ float red[8];
  const int b = (int)blockIdx.x, tid = threadIdx.x;
  const int lane = tid & 63, w = tid >> 6;
  float accum = 0.f;
  for (int t = 0; t < NDEC; t++) {
    const int row = t*BATCH + b;
    const float* pm = pmax + (size_t)row*NCHUNK;
    const float* ps = psum + (size_t)row*NCHUNK;
    float mx = -INFINITY;
    for (int c = tid; c < NCHUNK; c += 256) mx = fmaxf(mx, pm[c]);
#pragma unroll
    for (int m = 32; m >= 1; m >>= 1) mx = fmaxf(mx, __shfl_xor(mx, m, 64));
    if (lane == 0) red[w] = mx;
    __syncthreads();
    mx = fmaxf(fmaxf(red[0], red[1]), fmaxf(red[2], red[3]));
    __syncthreads();
    float sm = 0.f;
    for (int c = tid; c < NCHUNK; c += 256) sm += ps[c]*expf(pm[c] - mx);
#pragma unroll
    for (int m = 32; m >= 1; m >>= 1) sm += __shfl_xor(sm, m, 64);
    if (lane == 0) red[w] = sm;
    __syncthreads();
    sm = red[0] + red[1] + red[2] + red[3];
    __syncthreads();
    if (tid == 0) {
      const int tv = ptgt[(t + 1)*BATCH + b];
      if (tv != 0) accum += picked[row] - (mx + logf(sm));
    }
  }
  if (tid == 0) out[b] = accum;
}

// ---------------- host ----------------
extern "C" void kernel_launch(void* const* d_in, const int* in_sizes, int n_in,
                              void* d_out, int out_size, void* d_ws, size_t ws_size,
                              hipStream_t stream) {
  (void)in_sizes; (void)n_in; (void)out_size; (void)ws_size;
  const int*   p_src     = (const int*)d_in[0];
  const int*   p_tgt     = (const int*)d_in[1];
  const float* enc_masks = (const float*)d_in[2];
  const float* src_embed = (const float*)d_in[3];
  const float* tgt_embed = (const float*)d_in[4];
  const float* Wih_f = (const float*)d_in[5];
  const float* Whh_f = (const float*)d_in[6];
  const float* b_f   = (const float*)d_in[7];
  const float* Wih_b = (const float*)d_in[8];
  const float* Whh_b = (const float*)d_in[9];
  const float* b_b   = (const float*)d_in[10];
  const float* dWih  = (const float*)d_in[11];
  const float* dWhh  = (const float*)d_in[12];
  const float* db    = (const float*)d_in[13];
  const float* W_h   = (const float*)d_in[14];
  const float* W_c   = (const float*)d_in[15];
  const float* W_att = (const float*)d_in[16];
  const float* W_comb= (const float*)d_in[17];
  const float* W_voc = (const float*)d_in[18];
  float* out = (float*)d_out;

  float* p = (float*)d_ws;
  float* src_e    = p; p += S_LEN*BATCH*EMB;
  float* tgt_e    = p; p += NDEC*BATCH*EMB;
  float* xpf      = p; p += S_LEN*BATCH*G4H;
  float* xpb      = p; p += S_LEN*BATCH*G4H;
  float* dec_xp   = p; p += NDEC*BATCH*G4H;
  float* hpf      = p; p += S_LEN*BATCH*HID;        // packed [t][k/4][r][4]
  float* hpb      = p; p += S_LEN*BATCH*HID;
  float* hcat     = p; p += BATCH*2*HID;
  float* ccat     = p; p += BATCH*2*HID;
  float* ench     = p; p += BATCH*S_LEN*2*HID;
  float* encp     = p; p += BATCH*S_LEN*HID;
  float* h0       = p; p += BATCH*HID;
  float* c0       = p; p += BATCH*HID;
  float* aop      = p; p += 1024*BATCH;             // packed [k/4][r][4]
  float* xcomb    = p; p += 1536*BATCH;             // packed [k/4][r][4]
  float* outs     = p; p += (size_t)MPAD*HID;
  float* pmaxb    = p; p += (size_t)MPAD*NCHUNK;
  float* psumb    = p; p += (size_t)MPAD*NCHUNK;
  float* pickedb  = p; p += MPAD;

  // embeddings
  k_embed<<<S_LEN*BATCH + NDEC*BATCH, 256, 0, stream>>>(p_src, p_tgt, src_embed, tgt_embed, src_e, tgt_e);

  // batched input projections (bias folded)
  k_gemm<<<dim3(8, 40), 256, 0, stream>>>(src_e, Wih_f, b_f, xpf, G4H, EMB, EMB, 0);
  k_gemm<<<dim3(8, 40), 256, 0, stream>>>(src_e, Wih_b, b_b, xpb, G4H, EMB, EMB, 1);
  k_gemm<<<dim3(8, NDEC), 256, 0, stream>>>(tgt_e, dWih, db, dec_xp, G4H, EMB, 768, 0);

  // persistent bi-LSTM encoder
  {
    void* args[] = { (void*)&xpf, (void*)&xpb, (void*)&Whh_f, (void*)&Whh_b,
                     (void*)&hpf, (void*)&hpb, (void*)&hcat, (void*)&ccat };
    hipLaunchCooperativeKernel((void*)k_enc, dim3(256), dim3(256), args, 0, stream);
  }

  k_concat<<<BATCH*S_LEN, 256, 0, stream>>>(hpf, hpb, ench);

  // enc_proj, decoder init h/c
  k_gemm<<<dim3(2, 40), 256, 0, stream>>>(ench, W_att, nullptr, encp, HID, 2*HID, 2*HID, 0);
  k_gemm<<<dim3(2, 1), 256, 0, stream>>>(hcat, W_h, nullptr, h0, HID, 2*HID, 2*HID, 0);
  k_gemm<<<dim3(2, 1), 256, 0, stream>>>(ccat, W_c, nullptr, c0, HID, 2*HID, 2*HID, 0);

  // persistent decoder (LSTM + attention + combine)
  {
    void* args[] = { (void*)&dec_xp, (void*)&dWih, (void*)&dWhh, (void*)&W_comb,
                     (void*)&encp, (void*)&ench, (void*)&enc_masks, (void*)&h0, (void*)&c0,
                     (void*)&aop, (void*)&xcomb, (void*)&outs };
    hipLaunchCooperativeKernel((void*)k_dec, dim3(256), dim3(256), args, 0, stream);
  }

  // vocab projection + fused log-softmax
  k_vocab<<<dim3(NCHUNK, MPAD/64), 256, 0, stream>>>(outs, W_voc, p_tgt, pmaxb, psumb, pickedb);
  k_final<<<32, 256, 0, stream>>>(pmaxb, psumb, pickedb, p_tgt, out);
}